// Round 1
// baseline (131.096 us; speedup 1.0000x reference)
//
#include <hip/hip_runtime.h>
#include <hip/hip_bf16.h>

#define BB 4
#define NN 4096
#define DD 256
#define MM (BB * NN)      // 16384 rows total
#define MAXNZ 128

using bf16x8 = __attribute__((ext_vector_type(8))) __bf16;
using f32x4  = __attribute__((ext_vector_type(4))) float;

__device__ __forceinline__ unsigned short f2bf(float f) {
    union { float f; unsigned u; } x; x.f = f;
    unsigned r = x.u + 0x7fffu + ((x.u >> 16) & 1u);
    return (unsigned short)(r >> 16);
}
__device__ __forceinline__ float bf2f(unsigned short s) {
    union { unsigned u; float f; } x; x.u = ((unsigned)s) << 16;
    return x.f;
}

// ---------------- kernel 1: degree + compact column indices ----------------
__global__ __launch_bounds__(256) void k_deg(const float* __restrict__ adj,
                                             float* __restrict__ norm,
                                             int* __restrict__ cnt,
                                             unsigned short* __restrict__ idx) {
    const int row = blockIdx.x;                 // 0 .. MM-1
    const float4* arow = (const float4*)(adj + (size_t)row * NN);
    __shared__ int scount;
    __shared__ unsigned short sidx[MAXNZ];
    if (threadIdx.x == 0) scount = 0;
    __syncthreads();
#pragma unroll
    for (int r = 0; r < 4; ++r) {
        int v4 = threadIdx.x + 256 * r;         // 0..1023 float4 per row
        float4 v = arow[v4];
        int jb = v4 * 4;
        if (v.x != 0.f) { int p = atomicAdd(&scount, 1); if (p < MAXNZ) sidx[p] = (unsigned short)(jb + 0); }
        if (v.y != 0.f) { int p = atomicAdd(&scount, 1); if (p < MAXNZ) sidx[p] = (unsigned short)(jb + 1); }
        if (v.z != 0.f) { int p = atomicAdd(&scount, 1); if (p < MAXNZ) sidx[p] = (unsigned short)(jb + 2); }
        if (v.w != 0.f) { int p = atomicAdd(&scount, 1); if (p < MAXNZ) sidx[p] = (unsigned short)(jb + 3); }
    }
    __syncthreads();
    int c = scount < MAXNZ ? scount : MAXNZ;
    for (int t = threadIdx.x; t < c; t += 256) idx[(size_t)row * MAXNZ + t] = sidx[t];
    if (threadIdx.x == 0) {
        cnt[row] = c;
        norm[row] = rsqrtf((float)scount + 1e-6f);
    }
}

// ---------------- kernel 2: fused triple GEMM (bf16 MFMA) ----------------
// C[16384, 768] = x @ [theta | W_h | W_t]; epilogues differ per 256-col segment.
__global__ __launch_bounds__(256) void k_gemm3(const float* __restrict__ x,
                                               const float* __restrict__ theta,
                                               const float* __restrict__ Wh,
                                               const float* __restrict__ Wt,
                                               const float* __restrict__ bt,
                                               const float* __restrict__ norm,
                                               unsigned short* __restrict__ h,
                                               unsigned short* __restrict__ het,
                                               unsigned short* __restrict__ gate) {
    __shared__ __align__(16) unsigned short As[64][72];   // [m][k], padded
    __shared__ __align__(16) unsigned short Bs[64][72];   // [n][k] (transposed), padded

    const int tid = threadIdx.x;
    const int m0  = blockIdx.x * 64;
    const int seg = blockIdx.y >> 2;                      // 0:theta 1:Wh 2:Wt
    const int n0  = (blockIdx.y & 3) * 64;                // col within segment
    const float* W = (seg == 0) ? theta : ((seg == 1) ? Wh : Wt);

    const int wave = tid >> 6;
    const int lane = tid & 63;
    const int lm   = lane & 15;
    const int kg   = lane >> 4;                           // 0..3
    const int wm   = (wave >> 1) * 32;
    const int wn   = (wave & 1) * 32;

    f32x4 acc[2][2] = {};

    for (int kt = 0; kt < 4; ++kt) {
        const int k0 = kt * 64;
        // stage A tile 64x64 (fp32 -> bf16)
#pragma unroll
        for (int r = 0; r < 4; ++r) {
            int slot = tid + 256 * r;                     // 0..1023
            int mr = slot >> 4;
            int kc = (slot & 15) * 4;
            float4 v = *(const float4*)(x + (size_t)(m0 + mr) * DD + k0 + kc);
            unsigned short* dst = &As[mr][kc];
            dst[0] = f2bf(v.x); dst[1] = f2bf(v.y); dst[2] = f2bf(v.z); dst[3] = f2bf(v.w);
        }
        // stage B tile 64x64 transposed: W[k][n] -> Bs[n][k]
#pragma unroll
        for (int r = 0; r < 4; ++r) {
            int slot = tid + 256 * r;
            int kr = slot >> 4;
            int nc = (slot & 15) * 4;
            float4 v = *(const float4*)(W + (size_t)(k0 + kr) * DD + n0 + nc);
            Bs[nc + 0][kr] = f2bf(v.x);
            Bs[nc + 1][kr] = f2bf(v.y);
            Bs[nc + 2][kr] = f2bf(v.z);
            Bs[nc + 3][kr] = f2bf(v.w);
        }
        __syncthreads();
#pragma unroll
        for (int ks = 0; ks < 2; ++ks) {
            bf16x8 a[2], b[2];
#pragma unroll
            for (int i = 0; i < 2; ++i)
                a[i] = *(const bf16x8*)&As[wm + i * 16 + lm][ks * 32 + kg * 8];
#pragma unroll
            for (int j = 0; j < 2; ++j)
                b[j] = *(const bf16x8*)&Bs[wn + j * 16 + lm][ks * 32 + kg * 8];
#pragma unroll
            for (int i = 0; i < 2; ++i)
#pragma unroll
                for (int j = 0; j < 2; ++j)
                    acc[i][j] = __builtin_amdgcn_mfma_f32_16x16x32_bf16(a[i], b[j], acc[i][j], 0, 0, 0);
        }
        __syncthreads();
    }

    // epilogue: C frag mapping col = lane&15, row = (lane>>4)*4 + reg
    const int rbase = (lane >> 4) * 4;
#pragma unroll
    for (int i = 0; i < 2; ++i) {
#pragma unroll
        for (int j = 0; j < 2; ++j) {
            int gcol = n0 + wn + j * 16 + lm;             // 0..255 within segment
#pragma unroll
            for (int r = 0; r < 4; ++r) {
                int grow = m0 + wm + i * 16 + rbase + r;  // 0..16383
                float v = acc[i][j][r];
                size_t off = (size_t)grow * DD + gcol;
                if (seg == 0) {
                    h[off] = f2bf(v * norm[grow]);
                } else if (seg == 1) {
                    het[off] = f2bf(v);
                } else {
                    float g = 1.f / (1.f + expf(-(v + bt[gcol])));
                    gate[off] = f2bf(g);
                }
            }
        }
    }
}

// ---------------- kernel 3: gather-SpMM + blend + ELU ----------------
__global__ __launch_bounds__(256) void k_spmm(const unsigned short* __restrict__ h,
                                              const unsigned short* __restrict__ het,
                                              const unsigned short* __restrict__ gate,
                                              const float* __restrict__ norm,
                                              const int* __restrict__ cnt,
                                              const unsigned short* __restrict__ idx,
                                              float* __restrict__ out) {
    __shared__ int sj[MAXNZ];
    const int row = blockIdx.x;            // b*NN + i
    const int b   = row >> 12;
    const int d   = threadIdx.x;
    const int c   = cnt[row];
    const unsigned short* ip = idx + (size_t)row * MAXNZ;
    for (int t = threadIdx.x; t < c; t += 256) sj[t] = ip[t];
    __syncthreads();
    const unsigned short* hb = h + ((size_t)(b << 12)) * DD;
    float acc = 0.f;
    for (int t = 0; t < c; ++t)
        acc += bf2f(hb[(size_t)sj[t] * DD + d]);
    float fhom = acc * norm[row];
    size_t off = (size_t)row * DD + d;
    float fh = bf2f(het[off]);
    float g  = bf2f(gate[off]);
    float o  = g * fhom + (1.f - g) * fh;
    out[off] = (o > 0.f) ? o : (expf(o) - 1.f);
}

extern "C" void kernel_launch(void* const* d_in, const int* in_sizes, int n_in,
                              void* d_out, int out_size, void* d_ws, size_t ws_size,
                              hipStream_t stream) {
    const float* x     = (const float*)d_in[0];
    const float* adj   = (const float*)d_in[1];
    const float* theta = (const float*)d_in[2];
    const float* Wh    = (const float*)d_in[3];
    const float* Wt    = (const float*)d_in[4];
    const float* bt    = (const float*)d_in[5];
    float* out = (float*)d_out;

    char* w = (char*)d_ws;
    float* norm          = (float*)w;                                   // 64 KB
    int*   cnt           = (int*)(w + (size_t)MM * 4);                  // 64 KB
    unsigned short* idx  = (unsigned short*)(w + (size_t)MM * 8);       // 4 MB
    unsigned short* h    = (unsigned short*)(w + (size_t)MM * 8 + (size_t)MM * MAXNZ * 2);
    unsigned short* het  = h + (size_t)MM * DD;
    unsigned short* gate = het + (size_t)MM * DD;

    k_deg<<<dim3(MM), dim3(256), 0, stream>>>(adj, norm, cnt, idx);
    k_gemm3<<<dim3(MM / 64, 12), dim3(256), 0, stream>>>(x, theta, Wh, Wt, bt, norm, h, het, gate);
    k_spmm<<<dim3(MM), dim3(256), 0, stream>>>(h, het, gate, norm, cnt, idx, out);
}

// Round 3
// 122.708 us; speedup vs baseline: 1.0684x; 1.0684x over previous
//
#include <hip/hip_runtime.h>
#include <hip/hip_bf16.h>

#define BB 4
#define NN 4096
#define DD 256
#define MM (BB * NN)      // 16384 rows total
#define MAXNZ 128
#define WCAP 96           // per-wave compaction cap (mean ~8, 96 is >10 sigma)
#define GEMM_BLKS 3072    // 256 m-blocks x 12 (seg,n0)
#define TOTAL_BLKS (GEMM_BLKS + MM)   // 19456 = 1024 * 19

using bf16x8 = __attribute__((ext_vector_type(8))) __bf16;
using f32x4  = __attribute__((ext_vector_type(4))) float;

__device__ __forceinline__ unsigned short f2bf(float f) {
    union { float f; unsigned u; } x; x.f = f;
    unsigned r = x.u + 0x7fffu + ((x.u >> 16) & 1u);
    return (unsigned short)(r >> 16);
}
__device__ __forceinline__ float bf2f(unsigned short s) {
    union { unsigned u; float f; } x; x.u = ((unsigned)s) << 16;
    return x.f;
}

// ------------- fused kernel: deg scan (BW-bound) + triple GEMM (MFMA-bound) -------------
// Interleaved block roles (3 gemm : 16 deg per 19 blocks) so both are co-resident.
// Deg compaction is DETERMINISTIC: ballot+popcount prefix per wave, per-wave LDS
// partitions, cross-wave scan — no atomics, identical neighbor order every call.
__global__ __launch_bounds__(256) void k_prep(const float* __restrict__ x,
                                              const float* __restrict__ theta,
                                              const float* __restrict__ Wh,
                                              const float* __restrict__ Wt,
                                              const float* __restrict__ bt,
                                              const float* __restrict__ adj,
                                              float* __restrict__ norm,
                                              int* __restrict__ cnt,
                                              unsigned short* __restrict__ idx,
                                              unsigned short* __restrict__ h,
                                              unsigned short* __restrict__ het,
                                              unsigned short* __restrict__ gate) {
    __shared__ __align__(16) unsigned short As[64][72];   // gemm: [m][k], padded
    __shared__ __align__(16) unsigned short Bs[64][72];   // gemm: [n][k], padded
    __shared__ unsigned short part[4][WCAP];              // deg: per-wave compacted cols
    __shared__ int wcnt[4];                               // deg: per-wave true counts

    const int bx = blockIdx.x;
    const int q  = bx / 19;
    const int r  = bx % 19;
    const int tid = threadIdx.x;

    if (r < 3) {
        // ---------------- GEMM role ----------------
        const int g   = q * 3 + r;            // 0..3071
        const int m0  = (g & 255) * 64;
        const int yb  = g >> 8;               // 0..11
        const int seg = yb >> 2;              // 0:theta 1:Wh 2:Wt
        const int n0  = (yb & 3) * 64;
        const float* W = (seg == 0) ? theta : ((seg == 1) ? Wh : Wt);

        const int wave = tid >> 6;
        const int lane = tid & 63;
        const int lm   = lane & 15;
        const int kg   = lane >> 4;
        const int wm   = (wave >> 1) * 32;
        const int wn   = (wave & 1) * 32;

        f32x4 acc[2][2] = {};

        for (int kt = 0; kt < 4; ++kt) {
            const int k0 = kt * 64;
#pragma unroll
            for (int rr = 0; rr < 4; ++rr) {
                int slot = tid + 256 * rr;
                int mr = slot >> 4;
                int kc = (slot & 15) * 4;
                float4 v = *(const float4*)(x + (size_t)(m0 + mr) * DD + k0 + kc);
                unsigned short* dst = &As[mr][kc];
                dst[0] = f2bf(v.x); dst[1] = f2bf(v.y); dst[2] = f2bf(v.z); dst[3] = f2bf(v.w);
            }
#pragma unroll
            for (int rr = 0; rr < 4; ++rr) {
                int slot = tid + 256 * rr;
                int kr = slot >> 4;
                int nc = (slot & 15) * 4;
                float4 v = *(const float4*)(W + (size_t)(k0 + kr) * DD + n0 + nc);
                Bs[nc + 0][kr] = f2bf(v.x);
                Bs[nc + 1][kr] = f2bf(v.y);
                Bs[nc + 2][kr] = f2bf(v.z);
                Bs[nc + 3][kr] = f2bf(v.w);
            }
            __syncthreads();
#pragma unroll
            for (int ks = 0; ks < 2; ++ks) {
                bf16x8 a[2], b[2];
#pragma unroll
                for (int i = 0; i < 2; ++i)
                    a[i] = *(const bf16x8*)&As[wm + i * 16 + lm][ks * 32 + kg * 8];
#pragma unroll
                for (int j = 0; j < 2; ++j)
                    b[j] = *(const bf16x8*)&Bs[wn + j * 16 + lm][ks * 32 + kg * 8];
#pragma unroll
                for (int i = 0; i < 2; ++i)
#pragma unroll
                    for (int j = 0; j < 2; ++j)
                        acc[i][j] = __builtin_amdgcn_mfma_f32_16x16x32_bf16(a[i], b[j], acc[i][j], 0, 0, 0);
            }
            __syncthreads();
        }

        const int rbase = (lane >> 4) * 4;
#pragma unroll
        for (int i = 0; i < 2; ++i) {
#pragma unroll
            for (int j = 0; j < 2; ++j) {
                int gcol = n0 + wn + j * 16 + lm;
#pragma unroll
                for (int rr = 0; rr < 4; ++rr) {
                    int grow = m0 + wm + i * 16 + rbase + rr;
                    float v = acc[i][j][rr];
                    size_t off = (size_t)grow * DD + gcol;
                    if (seg == 0) {
                        h[off] = f2bf(v);                       // unscaled; norm applied in spmm
                    } else if (seg == 1) {
                        het[off] = f2bf(v);
                    } else {
                        float gt = 1.f / (1.f + expf(-(v + bt[gcol])));
                        gate[off] = f2bf(gt);
                    }
                }
            }
        }
    } else {
        // ---------------- deg role (deterministic ballot compaction) ----------------
        const int row  = q * 16 + (r - 3);    // 0..16383
        const int wave = tid >> 6;
        const int lane = tid & 63;
        const float4* arow4 = (const float4*)(adj + (size_t)row * NN);
        const unsigned long long lmask = (1ull << lane) - 1ull;
        unsigned int cw = 0;                  // this wave's running true count
        const int cbase = wave * 1024;        // column range [cbase, cbase+1024)
#pragma unroll
        for (int s = 0; s < 4; ++s) {
            float4 v = arow4[wave * 256 + s * 64 + lane];
            int col = cbase + s * 256 + lane * 4;
            unsigned long long m;
            int p;
            m = __ballot(v.x != 0.f);
            if (v.x != 0.f) { p = cw + __popcll(m & lmask); if (p < WCAP) part[wave][p] = (unsigned short)(col + 0); }
            cw += (unsigned)__popcll(m);
            m = __ballot(v.y != 0.f);
            if (v.y != 0.f) { p = cw + __popcll(m & lmask); if (p < WCAP) part[wave][p] = (unsigned short)(col + 1); }
            cw += (unsigned)__popcll(m);
            m = __ballot(v.z != 0.f);
            if (v.z != 0.f) { p = cw + __popcll(m & lmask); if (p < WCAP) part[wave][p] = (unsigned short)(col + 2); }
            cw += (unsigned)__popcll(m);
            m = __ballot(v.w != 0.f);
            if (v.w != 0.f) { p = cw + __popcll(m & lmask); if (p < WCAP) part[wave][p] = (unsigned short)(col + 3); }
            cw += (unsigned)__popcll(m);
        }
        if (lane == 0) wcnt[wave] = (int)cw;
        __syncthreads();
        const int w0 = wcnt[0], w1 = wcnt[1], w2 = wcnt[2], w3 = wcnt[3];
        const int total = w0 + w1 + w2 + w3;
        const int l0 = w0 < WCAP ? w0 : WCAP;
        const int l1 = w1 < WCAP ? w1 : WCAP;
        const int l2 = w2 < WCAP ? w2 : WCAP;
        const int l3 = w3 < WCAP ? w3 : WCAP;
        const int base1 = l0, base2 = l0 + l1, base3 = l0 + l1 + l2;
        int c = base3 + l3;
        if (c > MAXNZ) c = MAXNZ;
        for (int t = tid; t < c; t += 256) {
            int seg2, off2;
            if (t >= base3)      { seg2 = 3; off2 = t - base3; }
            else if (t >= base2) { seg2 = 2; off2 = t - base2; }
            else if (t >= base1) { seg2 = 1; off2 = t - base1; }
            else                 { seg2 = 0; off2 = t; }
            idx[(size_t)row * MAXNZ + t] = part[seg2][off2];
        }
        if (tid == 0) {
            cnt[row] = c;
            norm[row] = rsqrtf((float)total + 1e-6f);
        }
    }
}

// ---------------- kernel 2: gather-SpMM + blend + ELU (wave per row) ----------------
__global__ __launch_bounds__(256) void k_spmm(const unsigned short* __restrict__ h,
                                              const unsigned short* __restrict__ het,
                                              const unsigned short* __restrict__ gate,
                                              const float* __restrict__ norm,
                                              const int* __restrict__ cnt,
                                              const unsigned short* __restrict__ idx,
                                              float* __restrict__ out) {
    __shared__ unsigned short sj[4][MAXNZ];
    __shared__ float sn[4][MAXNZ];
    const int wave = threadIdx.x >> 6;
    const int lane = threadIdx.x & 63;
    const int row  = blockIdx.x * 4 + wave;
    const int b    = row >> 12;
    int c = cnt[row];
    if (c > MAXNZ) c = MAXNZ;
    const unsigned short* ip = idx + (size_t)row * MAXNZ;
    const float* nb = norm + (b << 12);
    for (int t = lane; t < c; t += 64) {
        unsigned short j = ip[t];
        sj[wave][t] = j;
        sn[wave][t] = nb[j];
    }
    __syncthreads();

    const unsigned short* hp = h + ((size_t)(b << 12)) * DD + lane * 4;
    f32x4 acc = {0.f, 0.f, 0.f, 0.f};
    int t = 0;
    for (; t + 4 <= c; t += 4) {
        int j0 = sj[wave][t + 0]; float w0 = sn[wave][t + 0];
        int j1 = sj[wave][t + 1]; float w1 = sn[wave][t + 1];
        int j2 = sj[wave][t + 2]; float w2 = sn[wave][t + 2];
        int j3 = sj[wave][t + 3]; float w3 = sn[wave][t + 3];
        ushort4 v0 = *(const ushort4*)(hp + (size_t)j0 * DD);
        ushort4 v1 = *(const ushort4*)(hp + (size_t)j1 * DD);
        ushort4 v2 = *(const ushort4*)(hp + (size_t)j2 * DD);
        ushort4 v3 = *(const ushort4*)(hp + (size_t)j3 * DD);
        acc.x += w0 * bf2f(v0.x) + w1 * bf2f(v1.x) + w2 * bf2f(v2.x) + w3 * bf2f(v3.x);
        acc.y += w0 * bf2f(v0.y) + w1 * bf2f(v1.y) + w2 * bf2f(v2.y) + w3 * bf2f(v3.y);
        acc.z += w0 * bf2f(v0.z) + w1 * bf2f(v1.z) + w2 * bf2f(v2.z) + w3 * bf2f(v3.z);
        acc.w += w0 * bf2f(v0.w) + w1 * bf2f(v1.w) + w2 * bf2f(v2.w) + w3 * bf2f(v3.w);
    }
    for (; t < c; ++t) {
        int j = sj[wave][t]; float wv = sn[wave][t];
        ushort4 v = *(const ushort4*)(hp + (size_t)j * DD);
        acc.x += wv * bf2f(v.x);
        acc.y += wv * bf2f(v.y);
        acc.z += wv * bf2f(v.z);
        acc.w += wv * bf2f(v.w);
    }

    const float nrm = norm[row];
    const size_t off = (size_t)row * DD + lane * 4;
    ushort4 hv = *(const ushort4*)(het + off);
    ushort4 gv = *(const ushort4*)(gate + off);
    float4 o;
    {
        float fhom, fh, g, val;
        fhom = acc.x * nrm; fh = bf2f(hv.x); g = bf2f(gv.x);
        val = g * fhom + (1.f - g) * fh; o.x = (val > 0.f) ? val : (expf(val) - 1.f);
        fhom = acc.y * nrm; fh = bf2f(hv.y); g = bf2f(gv.y);
        val = g * fhom + (1.f - g) * fh; o.y = (val > 0.f) ? val : (expf(val) - 1.f);
        fhom = acc.z * nrm; fh = bf2f(hv.z); g = bf2f(gv.z);
        val = g * fhom + (1.f - g) * fh; o.z = (val > 0.f) ? val : (expf(val) - 1.f);
        fhom = acc.w * nrm; fh = bf2f(hv.w); g = bf2f(gv.w);
        val = g * fhom + (1.f - g) * fh; o.w = (val > 0.f) ? val : (expf(val) - 1.f);
    }
    *(float4*)(out + off) = o;
}

extern "C" void kernel_launch(void* const* d_in, const int* in_sizes, int n_in,
                              void* d_out, int out_size, void* d_ws, size_t ws_size,
                              hipStream_t stream) {
    const float* x     = (const float*)d_in[0];
    const float* adj   = (const float*)d_in[1];
    const float* theta = (const float*)d_in[2];
    const float* Wh    = (const float*)d_in[3];
    const float* Wt    = (const float*)d_in[4];
    const float* bt    = (const float*)d_in[5];
    float* out = (float*)d_out;

    char* w = (char*)d_ws;
    float* norm          = (float*)w;                                   // 64 KB
    int*   cnt           = (int*)(w + (size_t)MM * 4);                  // 64 KB
    unsigned short* idx  = (unsigned short*)(w + (size_t)MM * 8);       // 4 MB
    unsigned short* h    = (unsigned short*)(w + (size_t)MM * 8 + (size_t)MM * MAXNZ * 2);
    unsigned short* het  = h + (size_t)MM * DD;
    unsigned short* gate = het + (size_t)MM * DD;

    k_prep<<<dim3(TOTAL_BLKS), dim3(256), 0, stream>>>(x, theta, Wh, Wt, bt, adj,
                                                       norm, cnt, idx, h, het, gate);
    k_spmm<<<dim3(MM / 4), dim3(256), 0, stream>>>(h, het, gate, norm, cnt, idx, out);
}